// Round 2
// baseline (93.363 us; speedup 1.0000x reference)
//
#include <hip/hip_runtime.h>

constexpr int OBS   = 682;   // 210 view + 32 feat + 440 nb
constexpr int ACTN  = 21;
constexpr int C1W_N = 1440;  // 32*5*3*3
constexpr int C2W_N = 9216;  // 32*32*3*3

// Transpose conv weights: [oc][k] -> [k][oc]  (k = c*9 + kh*3 + kw)
__global__ void transpose_w_k(const float* __restrict__ c1w,
                              const float* __restrict__ c2w,
                              float* __restrict__ ws) {
    int idx = blockIdx.x * 256 + threadIdx.x;
    if (idx < C1W_N) {
        int oc = idx / 45, x = idx - oc * 45;
        ws[x * 32 + oc] = c1w[idx];
    }
    int i2 = idx - C1W_N;
    if (i2 >= 0 && i2 < C2W_N) {
        int oc = i2 / 288, x = i2 - oc * 288;
        ws[C1W_N + x * 32 + oc] = c2w[i2];
    }
}

__device__ __forceinline__ float comp4(float4 v, int i) {
    return (i == 0) ? v.x : (i == 1) ? v.y : (i == 2) ? v.z : v.w;
}

template <bool TW>
__global__ __launch_bounds__(64, 4) void fused_k(
    const float* __restrict__ obs,
    const float* __restrict__ c1w, const float* __restrict__ c1b,
    const float* __restrict__ c2w, const float* __restrict__ c2b,
    const float* __restrict__ f1w, const float* __restrict__ f1b,
    const float* __restrict__ f2w, const float* __restrict__ f2b,
    const float* __restrict__ f3w, const float* __restrict__ f3b,
    const float* __restrict__ wt,
    float* __restrict__ out)
{
    const int b = blockIdx.x;
    const int t = threadIdx.x;

    __shared__ __align__(16) float s_obs[OBS];      // view | feat | nb
    __shared__ __align__(16) float s_c1d[2][640];   // [shift][ic*20 + h*4 + c]; shift1 = cols 1..4(3 valid)
    __shared__ __align__(16) float s_c2[192];       // [oc][pos]
    __shared__ __align__(16) float s_x[64];
    __shared__ __align__(16) float s_h[64];
    __shared__ int s_meta[20];

    const float* orow = obs + (long)b * OBS;
    for (int i = t; i < OBS; i += 64) s_obs[i] = orow[i];
    __syncthreads();

    // ---------------- agent meta scan (acts are one-hot or all-zero) ----------------
    if (t < 20) {
        const float* nb = &s_obs[242 + t * 22];
        int id = (int)nb[0];
        int js = -1;
        #pragma unroll
        for (int j = 0; j < ACTN; ++j) {
            float av = nb[1 + j];
            js = (av != 0.f && js < 0) ? j : js;
        }
        // mode: 0 invalid(skip), 1 expand, 2 single
        int mode = (id < -1) ? 0 : ((id >= 0 && js < 0) ? 1 : 2);
        s_meta[t] = ((id + 2) << 8) | (mode << 5) | (js + 1);
    }

    // ---------------- conv1: (5,7,6) -> (32,5,4), relu ----------------
    {
        const int oc = t & 31, ph = t >> 5;   // ow in {ph, ph+2}
        float acc[10];
        #pragma unroll
        for (int i = 0; i < 10; ++i) acc[i] = 0.f;
        #pragma unroll
        for (int c = 0; c < 5; ++c) {
            float w[9];
            #pragma unroll
            for (int k = 0; k < 9; ++k)
                w[k] = TW ? wt[(c * 9 + k) * 32 + oc] : c1w[oc * 45 + c * 9 + k];
            #pragma unroll
            for (int r = 0; r < 7; ++r) {
                float rv[5];
                #pragma unroll
                for (int j = 0; j < 5; ++j) rv[j] = s_obs[c * 42 + r * 6 + ph + j];
                #pragma unroll
                for (int kh = 0; kh < 3; ++kh) {
                    int oh = r - kh;
                    if (oh < 0 || oh > 4) continue;
                    #pragma unroll
                    for (int kw = 0; kw < 3; ++kw) {
                        acc[oh * 2 + 0] = fmaf(rv[kw],     w[kh * 3 + kw], acc[oh * 2 + 0]);
                        acc[oh * 2 + 1] = fmaf(rv[kw + 2], w[kh * 3 + kw], acc[oh * 2 + 1]);
                    }
                }
            }
        }
        float bias = c1b[oc];
        #pragma unroll
        for (int oh = 0; oh < 5; ++oh)
            #pragma unroll
            for (int owi = 0; owi < 2; ++owi) {
                float v = fmaxf(acc[oh * 2 + owi] + bias, 0.f);
                int ow = ph + 2 * owi;
                s_c1d[0][oc * 20 + oh * 4 + ow] = v;
                if (ow >= 1) s_c1d[1][oc * 20 + oh * 4 + ow - 1] = v;
            }
    }
    __syncthreads();

    // ---------------- conv2: (32,5,4) -> (32,3,2), relu  (all 64 lanes) ----------------
    {
        const int oc = t & 31, g = t >> 5;   // g = ow; half-wave g=1 uses shifted copy
        const float* src = &s_c1d[g][0];
        float a0 = 0.f, a1 = 0.f, a2 = 0.f;  // oh = 0,1,2 at ow=g
        #pragma unroll 4
        for (int ic = 0; ic < 32; ++ic) {
            const float4* rp = (const float4*)(src + ic * 20);
            float4 r0 = rp[0], r1 = rp[1], r2 = rp[2], r3 = rp[3], r4 = rp[4];
            float w[9];
            #pragma unroll
            for (int k = 0; k < 9; ++k)
                w[k] = TW ? wt[C1W_N + (ic * 9 + k) * 32 + oc] : c2w[oc * 288 + ic * 9 + k];
            #pragma unroll
            for (int kh = 0; kh < 3; ++kh) {
                float4 ra = (kh == 0) ? r0 : (kh == 1) ? r1 : r2; // row kh   (oh=0)
                float4 rb = (kh == 0) ? r1 : (kh == 1) ? r2 : r3; // row kh+1 (oh=1)
                float4 rc = (kh == 0) ? r2 : (kh == 1) ? r3 : r4; // row kh+2 (oh=2)
                #pragma unroll
                for (int kw = 0; kw < 3; ++kw) {
                    float ww = w[kh * 3 + kw];
                    a0 = fmaf(comp4(ra, kw), ww, a0);
                    a1 = fmaf(comp4(rb, kw), ww, a1);
                    a2 = fmaf(comp4(rc, kw), ww, a2);
                }
            }
        }
        float bias = c2b[oc];
        s_c2[oc * 6 + 0 + g] = fmaxf(a0 + bias, 0.f);
        s_c2[oc * 6 + 2 + g] = fmaxf(a1 + bias, 0.f);
        s_c2[oc * 6 + 4 + g] = fmaxf(a2 + bias, 0.f);
    }
    __syncthreads();

    // ---------------- fc1: 192 -> 64, relu (4 accumulators) ----------------
    {
        float a0 = f1b[t], a1 = 0.f, a2 = 0.f, a3 = 0.f;
        const float4* xp = (const float4*)s_c2;
        #pragma unroll
        for (int i = 0; i < 48; i += 4) {
            float4 v0 = xp[i], v1 = xp[i + 1], v2 = xp[i + 2], v3 = xp[i + 3];
            a0 = fmaf(v0.x, f1w[((i    ) * 4 + 0) * 64 + t], a0);
            a0 = fmaf(v0.y, f1w[((i    ) * 4 + 1) * 64 + t], a0);
            a0 = fmaf(v0.z, f1w[((i    ) * 4 + 2) * 64 + t], a0);
            a0 = fmaf(v0.w, f1w[((i    ) * 4 + 3) * 64 + t], a0);
            a1 = fmaf(v1.x, f1w[((i + 1) * 4 + 0) * 64 + t], a1);
            a1 = fmaf(v1.y, f1w[((i + 1) * 4 + 1) * 64 + t], a1);
            a1 = fmaf(v1.z, f1w[((i + 1) * 4 + 2) * 64 + t], a1);
            a1 = fmaf(v1.w, f1w[((i + 1) * 4 + 3) * 64 + t], a1);
            a2 = fmaf(v2.x, f1w[((i + 2) * 4 + 0) * 64 + t], a2);
            a2 = fmaf(v2.y, f1w[((i + 2) * 4 + 1) * 64 + t], a2);
            a2 = fmaf(v2.z, f1w[((i + 2) * 4 + 2) * 64 + t], a2);
            a2 = fmaf(v2.w, f1w[((i + 2) * 4 + 3) * 64 + t], a2);
            a3 = fmaf(v3.x, f1w[((i + 3) * 4 + 0) * 64 + t], a3);
            a3 = fmaf(v3.y, f1w[((i + 3) * 4 + 1) * 64 + t], a3);
            a3 = fmaf(v3.z, f1w[((i + 3) * 4 + 2) * 64 + t], a3);
            a3 = fmaf(v3.w, f1w[((i + 3) * 4 + 3) * 64 + t], a3);
        }
        s_x[t] = fmaxf((a0 + a1) + (a2 + a3), 0.f);
    }
    __syncthreads();

    // ---------------- base = x@W2x + feat@W2f + b2 (4 accumulators) ----------------
    float base_t;
    {
        const float* W2x = f2w;             // rows [0,64)
        const float* W2f = f2w + 64 * 64;   // rows [64,96)
        float a0 = f2b[t], a1 = 0.f, a2 = 0.f, a3 = 0.f;
        const float4* xp = (const float4*)s_x;
        #pragma unroll
        for (int i = 0; i < 16; i += 4) {
            float4 v0 = xp[i], v1 = xp[i + 1], v2 = xp[i + 2], v3 = xp[i + 3];
            a0 = fmaf(v0.x, W2x[((i    ) * 4 + 0) * 64 + t], a0);
            a0 = fmaf(v0.y, W2x[((i    ) * 4 + 1) * 64 + t], a0);
            a0 = fmaf(v0.z, W2x[((i    ) * 4 + 2) * 64 + t], a0);
            a0 = fmaf(v0.w, W2x[((i    ) * 4 + 3) * 64 + t], a0);
            a1 = fmaf(v1.x, W2x[((i + 1) * 4 + 0) * 64 + t], a1);
            a1 = fmaf(v1.y, W2x[((i + 1) * 4 + 1) * 64 + t], a1);
            a1 = fmaf(v1.z, W2x[((i + 1) * 4 + 2) * 64 + t], a1);
            a1 = fmaf(v1.w, W2x[((i + 1) * 4 + 3) * 64 + t], a1);
            a2 = fmaf(v2.x, W2x[((i + 2) * 4 + 0) * 64 + t], a2);
            a2 = fmaf(v2.y, W2x[((i + 2) * 4 + 1) * 64 + t], a2);
            a2 = fmaf(v2.z, W2x[((i + 2) * 4 + 2) * 64 + t], a2);
            a2 = fmaf(v2.w, W2x[((i + 2) * 4 + 3) * 64 + t], a2);
            a3 = fmaf(v3.x, W2x[((i + 3) * 4 + 0) * 64 + t], a3);
            a3 = fmaf(v3.y, W2x[((i + 3) * 4 + 1) * 64 + t], a3);
            a3 = fmaf(v3.z, W2x[((i + 3) * 4 + 2) * 64 + t], a3);
            a3 = fmaf(v3.w, W2x[((i + 3) * 4 + 3) * 64 + t], a3);
        }
        const float4* fp = (const float4*)&s_obs[208];   // feat at [210,242); use scalar-safe path below
        (void)fp;
        const float2* f2p = (const float2*)&s_obs[210];  // 8B-aligned (210 even)
        #pragma unroll
        for (int i = 0; i < 16; i += 4) {
            float2 v0 = f2p[i], v1 = f2p[i + 1], v2 = f2p[i + 2], v3 = f2p[i + 3];
            a0 = fmaf(v0.x, W2f[((i    ) * 2 + 0) * 64 + t], a0);
            a0 = fmaf(v0.y, W2f[((i    ) * 2 + 1) * 64 + t], a0);
            a1 = fmaf(v1.x, W2f[((i + 1) * 2 + 0) * 64 + t], a1);
            a1 = fmaf(v1.y, W2f[((i + 1) * 2 + 1) * 64 + t], a1);
            a2 = fmaf(v2.x, W2f[((i + 2) * 2 + 0) * 64 + t], a2);
            a2 = fmaf(v2.y, W2f[((i + 2) * 2 + 1) * 64 + t], a2);
            a3 = fmaf(v3.x, W2f[((i + 3) * 2 + 0) * 64 + t], a3);
            a3 = fmaf(v3.y, W2f[((i + 3) * 2 + 1) * 64 + t], a3);
        }
        base_t = (a0 + a1) + (a2 + a3);
    }

    // ---------------- agents ----------------
    const float* W2id  = f2w + 96 * 64;
    const float* W2act = f2w + 116 * 64;
    float w2a[ACTN];
    #pragma unroll
    for (int j = 0; j < ACTN; ++j) w2a[j] = W2act[j * 64 + t];

    float hacc = 0.f, cnt = 0.f;
    #pragma unroll
    for (int a = 0; a < 20; ++a) {
        int m = s_meta[a];
        int mode = (m >> 5) & 3;
        if (mode == 0) continue;                    // wave-uniform
        int id = (m >> 8) - 2;
        int js = (m & 31) - 1;
        float idr = (id >= 0) ? W2id[id * 64 + t] : 0.f;
        float u = base_t + idr;
        if (mode == 1) {                            // expand: sum_j relu(u + W2act[j])
            float h0 = 0.f, h1 = 0.f, h2 = 0.f;
            #pragma unroll
            for (int j = 0; j < ACTN; j += 3) {
                h0 += fmaxf(u + w2a[j],     0.f);
                h1 += fmaxf(u + w2a[j + 1], 0.f);
                h2 += fmaxf(u + w2a[j + 2], 0.f);
            }
            hacc += (h0 + h1) + h2;
            cnt  += 21.f;
        } else {                                    // single action (or none, id==-1)
            float ar = (js >= 0) ? W2act[js * 64 + t] : 0.f;
            hacc += fmaxf(u + ar, 0.f);
            cnt  += 1.f;
        }
    }
    s_h[t] = hacc;
    __syncthreads();

    // ---------------- final: q = hacc @ fc3_w + cnt*fc3_b ----------------
    if (t < ACTN) {
        float q0 = cnt * f3b[t], q1 = 0.f, q2 = 0.f, q3 = 0.f;
        const float4* hp = (const float4*)s_h;
        #pragma unroll
        for (int h = 0; h < 16; h += 4) {
            float4 v0 = hp[h], v1 = hp[h + 1], v2 = hp[h + 2], v3 = hp[h + 3];
            q0 = fmaf(v0.x, f3w[((h    ) * 4 + 0) * 21 + t], q0);
            q0 = fmaf(v0.y, f3w[((h    ) * 4 + 1) * 21 + t], q0);
            q0 = fmaf(v0.z, f3w[((h    ) * 4 + 2) * 21 + t], q0);
            q0 = fmaf(v0.w, f3w[((h    ) * 4 + 3) * 21 + t], q0);
            q1 = fmaf(v1.x, f3w[((h + 1) * 4 + 0) * 21 + t], q1);
            q1 = fmaf(v1.y, f3w[((h + 1) * 4 + 1) * 21 + t], q1);
            q1 = fmaf(v1.z, f3w[((h + 1) * 4 + 2) * 21 + t], q1);
            q1 = fmaf(v1.w, f3w[((h + 1) * 4 + 3) * 21 + t], q1);
            q2 = fmaf(v2.x, f3w[((h + 2) * 4 + 0) * 21 + t], q2);
            q2 = fmaf(v2.y, f3w[((h + 2) * 4 + 1) * 21 + t], q2);
            q2 = fmaf(v2.z, f3w[((h + 2) * 4 + 2) * 21 + t], q2);
            q2 = fmaf(v2.w, f3w[((h + 2) * 4 + 3) * 21 + t], q2);
            q3 = fmaf(v3.x, f3w[((h + 3) * 4 + 0) * 21 + t], q3);
            q3 = fmaf(v3.y, f3w[((h + 3) * 4 + 1) * 21 + t], q3);
            q3 = fmaf(v3.z, f3w[((h + 3) * 4 + 2) * 21 + t], q3);
            q3 = fmaf(v3.w, f3w[((h + 3) * 4 + 3) * 21 + t], q3);
        }
        out[b * 21 + t] = (q0 + q1) + (q2 + q3);
    }
}

extern "C" void kernel_launch(void* const* d_in, const int* in_sizes, int n_in,
                              void* d_out, int out_size, void* d_ws, size_t ws_size,
                              hipStream_t stream) {
    const float* obs = (const float*)d_in[0];
    const float* c1w = (const float*)d_in[1];
    const float* c1b = (const float*)d_in[2];
    const float* c2w = (const float*)d_in[3];
    const float* c2b = (const float*)d_in[4];
    const float* f1w = (const float*)d_in[5];
    const float* f1b = (const float*)d_in[6];
    const float* f2w = (const float*)d_in[7];
    const float* f2b = (const float*)d_in[8];
    const float* f3w = (const float*)d_in[9];
    const float* f3b = (const float*)d_in[10];
    float* ws = (float*)d_ws;
    float* o  = (float*)d_out;

    const bool tw = ws_size >= (size_t)(C1W_N + C2W_N) * sizeof(float);
    if (tw) {
        transpose_w_k<<<(C1W_N + C2W_N + 255) / 256, 256, 0, stream>>>(c1w, c2w, ws);
        fused_k<true><<<4096, 64, 0, stream>>>(obs, c1w, c1b, c2w, c2b, f1w, f1b,
                                               f2w, f2b, f3w, f3b, ws, o);
    } else {
        fused_k<false><<<4096, 64, 0, stream>>>(obs, c1w, c1b, c2w, c2b, f1w, f1b,
                                                f2w, f2b, f3w, f3b, ws, o);
    }
}

// Round 3
// 88.516 us; speedup vs baseline: 1.0548x; 1.0548x over previous
//
#include <hip/hip_runtime.h>

constexpr int OBS  = 682;   // 210 view + 32 feat + 440 nb
constexpr int ACTN = 21;

// ---- repacked weight arena (float offsets in d_ws) ----
constexpr int OFF_C1  = 0;      // [c*3+q][oc][4]   c<5,q<3  (taps 4q+r, r<4, k=4q+r<9 else 0)
constexpr int OFF_C2  = 1920;   // [ic*3+q][oc][4]  ic<32
constexpr int OFF_F1  = 14208;  // [kq][t][4]       kq<48
constexpr int OFF_W2X = 26496;  // [kq][t][4]       kq<16
constexpr int OFF_W2F = 30592;  // [kq][t][4]       kq<8
constexpr int OFF_F3  = 32640;  // [hq][a21][4]     hq<16
constexpr int WS_FLOATS = 33984;

// segment starts in repack thread-index space
constexpr int SEG_C2 = 480, SEG_F1 = 3552, SEG_W2X = 6624, SEG_W2F = 7648, SEG_F3 = 8160, SEG_END = 8496;

__global__ void repack_k(const float* __restrict__ c1w, const float* __restrict__ c2w,
                         const float* __restrict__ f1w, const float* __restrict__ f2w,
                         const float* __restrict__ f3w, float* __restrict__ ws) {
    int idx = blockIdx.x * 256 + threadIdx.x;
    if (idx >= SEG_END) return;
    float4* ws4 = (float4*)ws;
    float v[4];
    if (idx < SEG_C2) {                       // conv1: q=idx/32 (c*3+qq), oc=idx%32
        int q = idx >> 5, oc = idx & 31, c = q / 3, qq = q % 3;
        #pragma unroll
        for (int r = 0; r < 4; ++r) {
            int k = 4 * qq + r;
            v[r] = (k < 9) ? c1w[oc * 45 + c * 9 + k] : 0.f;
        }
        ws4[(OFF_C1 >> 2) + q * 32 + oc] = make_float4(v[0], v[1], v[2], v[3]);
    } else if (idx < SEG_F1) {                // conv2
        int i = idx - SEG_C2;
        int q = i >> 5, oc = i & 31, ic = q / 3, qq = q % 3;
        #pragma unroll
        for (int r = 0; r < 4; ++r) {
            int k = 4 * qq + r;
            v[r] = (k < 9) ? c2w[oc * 288 + ic * 9 + k] : 0.f;
        }
        ws4[(OFF_C2 >> 2) + q * 32 + oc] = make_float4(v[0], v[1], v[2], v[3]);
    } else if (idx < SEG_W2X) {               // fc1
        int i = idx - SEG_F1;
        int kq = i >> 6, t = i & 63;
        #pragma unroll
        for (int r = 0; r < 4; ++r) v[r] = f1w[(4 * kq + r) * 64 + t];
        ws4[(OFF_F1 >> 2) + kq * 64 + t] = make_float4(v[0], v[1], v[2], v[3]);
    } else if (idx < SEG_W2F) {               // W2x = f2w rows [0,64)
        int i = idx - SEG_W2X;
        int kq = i >> 6, t = i & 63;
        #pragma unroll
        for (int r = 0; r < 4; ++r) v[r] = f2w[(4 * kq + r) * 64 + t];
        ws4[(OFF_W2X >> 2) + kq * 64 + t] = make_float4(v[0], v[1], v[2], v[3]);
    } else if (idx < SEG_F3) {                // W2f = f2w rows [64,96)
        int i = idx - SEG_W2F;
        int kq = i >> 6, t = i & 63;
        #pragma unroll
        for (int r = 0; r < 4; ++r) v[r] = f2w[(64 + 4 * kq + r) * 64 + t];
        ws4[(OFF_W2F >> 2) + kq * 64 + t] = make_float4(v[0], v[1], v[2], v[3]);
    } else {                                  // fc3
        int i = idx - SEG_F3;
        int hq = i / 21, a = i % 21;
        #pragma unroll
        for (int r = 0; r < 4; ++r) v[r] = f3w[(4 * hq + r) * 21 + a];
        ws4[(OFF_F3 >> 2) + hq * 21 + a] = make_float4(v[0], v[1], v[2], v[3]);
    }
}

__device__ __forceinline__ float comp4(float4 v, int i) {
    return (i == 0) ? v.x : (i == 1) ? v.y : (i == 2) ? v.z : v.w;
}

// LDS arena (floats)
constexpr int S_OBS = 0;     // 682
constexpr int S_C1D = 704;   // 2 x 640   (shift copies for conv2)
constexpr int S_C2  = 1984;  // 192
constexpr int S_X   = 2176;  // 64
constexpr int S_H   = 2240;  // 64
constexpr int S_W2A = 704;   // 1344, overlays C1D after fc1
constexpr int S_TOT = 2304;

template <bool TW>
__global__ __launch_bounds__(64, 4) void fused_k(
    const float* __restrict__ obs,
    const float* __restrict__ c1w, const float* __restrict__ c1b,
    const float* __restrict__ c2w, const float* __restrict__ c2b,
    const float* __restrict__ f1w, const float* __restrict__ f1b,
    const float* __restrict__ f2w, const float* __restrict__ f2b,
    const float* __restrict__ f3w, const float* __restrict__ f3b,
    const float* __restrict__ wt,
    float* __restrict__ out)
{
    const int b = blockIdx.x;
    const int t = threadIdx.x;

    __shared__ __align__(16) float sb[S_TOT];
    __shared__ int s_meta[20];
    const float4* wp = (const float4*)wt;

    // ---- stage obs row (float2, row base is 8B-aligned: 682 even) ----
    {
        const float2* src = (const float2*)(obs + (long)b * OBS);
        float2* dst = (float2*)sb;
        #pragma unroll
        for (int k = 0; k < 6; ++k) {
            int i = t + k * 64;
            if (i < 341) dst[i] = src[i];
        }
    }
    __syncthreads();

    // ---- agent meta scan (acts one-hot or zero) ----
    if (t < 20) {
        const float* nb = &sb[S_OBS + 242 + t * 22];
        int id = (int)nb[0];
        int js = -1;
        #pragma unroll
        for (int j = 0; j < ACTN; ++j) {
            float av = nb[1 + j];
            js = (av != 0.f && js < 0) ? j : js;
        }
        int mode = (id < -1) ? 0 : ((id >= 0 && js < 0) ? 1 : 2);
        s_meta[t] = ((id + 2) << 8) | (mode << 5) | (js + 1);
    }

    // ---- conv1: (5,7,6) -> (32,5,4), relu; dual-shift copies ----
    {
        const int oc = t & 31, ph = t >> 5;       // ow in {ph, ph+2}
        float acc[10];
        #pragma unroll
        for (int i = 0; i < 10; ++i) acc[i] = 0.f;
        #pragma unroll
        for (int c = 0; c < 5; ++c) {
            float w[9];
            if constexpr (TW) {
                float4 w0 = wp[(OFF_C1 >> 2) + (c * 3 + 0) * 32 + oc];
                float4 w1 = wp[(OFF_C1 >> 2) + (c * 3 + 1) * 32 + oc];
                float4 w2 = wp[(OFF_C1 >> 2) + (c * 3 + 2) * 32 + oc];
                w[0] = w0.x; w[1] = w0.y; w[2] = w0.z; w[3] = w0.w;
                w[4] = w1.x; w[5] = w1.y; w[6] = w1.z; w[7] = w1.w;
                w[8] = w2.x;
            } else {
                #pragma unroll
                for (int k = 0; k < 9; ++k) w[k] = c1w[oc * 45 + c * 9 + k];
            }
            #pragma unroll
            for (int r = 0; r < 7; ++r) {
                float rv[5];
                #pragma unroll
                for (int j = 0; j < 5; ++j) rv[j] = sb[S_OBS + c * 42 + r * 6 + ph + j];
                #pragma unroll
                for (int kh = 0; kh < 3; ++kh) {
                    int oh = r - kh;
                    if (oh < 0 || oh > 4) continue;
                    #pragma unroll
                    for (int kw = 0; kw < 3; ++kw) {
                        acc[oh * 2 + 0] = fmaf(rv[kw],     w[kh * 3 + kw], acc[oh * 2 + 0]);
                        acc[oh * 2 + 1] = fmaf(rv[kw + 2], w[kh * 3 + kw], acc[oh * 2 + 1]);
                    }
                }
            }
        }
        float bias = c1b[oc];
        #pragma unroll
        for (int oh = 0; oh < 5; ++oh)
            #pragma unroll
            for (int owi = 0; owi < 2; ++owi) {
                float v = fmaxf(acc[oh * 2 + owi] + bias, 0.f);
                int ow = ph + 2 * owi;
                sb[S_C1D + oc * 20 + oh * 4 + ow] = v;
                if (ow >= 1) sb[S_C1D + 640 + oc * 20 + oh * 4 + ow - 1] = v;
            }
    }
    __syncthreads();

    // ---- conv2: (32,5,4) -> (32,3,2), relu; all 64 lanes ----
    {
        const int oc = t & 31, g = t >> 5;        // g = ow
        const float* src = &sb[S_C1D + g * 640];
        float a0 = 0.f, a1 = 0.f, a2 = 0.f;       // oh = 0,1,2
        #pragma unroll 4
        for (int ic = 0; ic < 32; ++ic) {
            const float4* rp = (const float4*)(src + ic * 20);
            float4 r0 = rp[0], r1 = rp[1], r2 = rp[2], r3 = rp[3], r4 = rp[4];
            float w[9];
            if constexpr (TW) {
                float4 w0 = wp[(OFF_C2 >> 2) + (ic * 3 + 0) * 32 + oc];
                float4 w1 = wp[(OFF_C2 >> 2) + (ic * 3 + 1) * 32 + oc];
                float4 w2 = wp[(OFF_C2 >> 2) + (ic * 3 + 2) * 32 + oc];
                w[0] = w0.x; w[1] = w0.y; w[2] = w0.z; w[3] = w0.w;
                w[4] = w1.x; w[5] = w1.y; w[6] = w1.z; w[7] = w1.w;
                w[8] = w2.x;
            } else {
                #pragma unroll
                for (int k = 0; k < 9; ++k) w[k] = c2w[oc * 288 + ic * 9 + k];
            }
            #pragma unroll
            for (int kh = 0; kh < 3; ++kh) {
                float4 ra = (kh == 0) ? r0 : (kh == 1) ? r1 : r2;
                float4 rb = (kh == 0) ? r1 : (kh == 1) ? r2 : r3;
                float4 rc = (kh == 0) ? r2 : (kh == 1) ? r3 : r4;
                #pragma unroll
                for (int kw = 0; kw < 3; ++kw) {
                    float ww = w[kh * 3 + kw];
                    a0 = fmaf(comp4(ra, kw), ww, a0);
                    a1 = fmaf(comp4(rb, kw), ww, a1);
                    a2 = fmaf(comp4(rc, kw), ww, a2);
                }
            }
        }
        float bias = c2b[oc];
        sb[S_C2 + oc * 6 + 0 + g] = fmaxf(a0 + bias, 0.f);
        sb[S_C2 + oc * 6 + 2 + g] = fmaxf(a1 + bias, 0.f);
        sb[S_C2 + oc * 6 + 4 + g] = fmaxf(a2 + bias, 0.f);
    }
    __syncthreads();

    // ---- fc1: 192 -> 64, relu ----
    {
        float a0 = f1b[t], a1 = 0.f, a2 = 0.f, a3 = 0.f;
        const float4* xp = (const float4*)&sb[S_C2];
        #pragma unroll
        for (int kq = 0; kq < 48; kq += 4) {
            float4 x0 = xp[kq], x1 = xp[kq + 1], x2 = xp[kq + 2], x3 = xp[kq + 3];
            float4 w0, w1, w2, w3;
            if constexpr (TW) {
                w0 = wp[(OFF_F1 >> 2) + (kq    ) * 64 + t];
                w1 = wp[(OFF_F1 >> 2) + (kq + 1) * 64 + t];
                w2 = wp[(OFF_F1 >> 2) + (kq + 2) * 64 + t];
                w3 = wp[(OFF_F1 >> 2) + (kq + 3) * 64 + t];
            } else {
                w0 = make_float4(f1w[(4*kq+0)*64+t],  f1w[(4*kq+1)*64+t],  f1w[(4*kq+2)*64+t],  f1w[(4*kq+3)*64+t]);
                w1 = make_float4(f1w[(4*kq+4)*64+t],  f1w[(4*kq+5)*64+t],  f1w[(4*kq+6)*64+t],  f1w[(4*kq+7)*64+t]);
                w2 = make_float4(f1w[(4*kq+8)*64+t],  f1w[(4*kq+9)*64+t],  f1w[(4*kq+10)*64+t], f1w[(4*kq+11)*64+t]);
                w3 = make_float4(f1w[(4*kq+12)*64+t], f1w[(4*kq+13)*64+t], f1w[(4*kq+14)*64+t], f1w[(4*kq+15)*64+t]);
            }
            a0 = fmaf(x0.x, w0.x, a0); a0 = fmaf(x0.y, w0.y, a0); a0 = fmaf(x0.z, w0.z, a0); a0 = fmaf(x0.w, w0.w, a0);
            a1 = fmaf(x1.x, w1.x, a1); a1 = fmaf(x1.y, w1.y, a1); a1 = fmaf(x1.z, w1.z, a1); a1 = fmaf(x1.w, w1.w, a1);
            a2 = fmaf(x2.x, w2.x, a2); a2 = fmaf(x2.y, w2.y, a2); a2 = fmaf(x2.z, w2.z, a2); a2 = fmaf(x2.w, w2.w, a2);
            a3 = fmaf(x3.x, w3.x, a3); a3 = fmaf(x3.y, w3.y, a3); a3 = fmaf(x3.z, w3.z, a3); a3 = fmaf(x3.w, w3.w, a3);
        }
        sb[S_X + t] = fmaxf((a0 + a1) + (a2 + a3), 0.f);
    }
    __syncthreads();

    // ---- stage W2act into LDS (overlays conv scratch; safe after fc1 sync) ----
    {
        const float4* src = (const float4*)(f2w + 116 * 64);
        float4* dst = (float4*)&sb[S_W2A];
        #pragma unroll
        for (int k = 0; k < 6; ++k) {
            int i = t + k * 64;
            if (i < 336) dst[i] = src[i];
        }
    }

    // ---- base = x@W2x + feat@W2f + b2 ----
    float base_t;
    {
        float a0 = f2b[t], a1 = 0.f, a2 = 0.f, a3 = 0.f;
        const float4* xp = (const float4*)&sb[S_X];
        #pragma unroll
        for (int kq = 0; kq < 16; kq += 4) {
            float4 x0 = xp[kq], x1 = xp[kq + 1], x2 = xp[kq + 2], x3 = xp[kq + 3];
            float4 w0, w1, w2, w3;
            if constexpr (TW) {
                w0 = wp[(OFF_W2X >> 2) + (kq    ) * 64 + t];
                w1 = wp[(OFF_W2X >> 2) + (kq + 1) * 64 + t];
                w2 = wp[(OFF_W2X >> 2) + (kq + 2) * 64 + t];
                w3 = wp[(OFF_W2X >> 2) + (kq + 3) * 64 + t];
            } else {
                w0 = make_float4(f2w[(4*kq+0)*64+t],  f2w[(4*kq+1)*64+t],  f2w[(4*kq+2)*64+t],  f2w[(4*kq+3)*64+t]);
                w1 = make_float4(f2w[(4*kq+4)*64+t],  f2w[(4*kq+5)*64+t],  f2w[(4*kq+6)*64+t],  f2w[(4*kq+7)*64+t]);
                w2 = make_float4(f2w[(4*kq+8)*64+t],  f2w[(4*kq+9)*64+t],  f2w[(4*kq+10)*64+t], f2w[(4*kq+11)*64+t]);
                w3 = make_float4(f2w[(4*kq+12)*64+t], f2w[(4*kq+13)*64+t], f2w[(4*kq+14)*64+t], f2w[(4*kq+15)*64+t]);
            }
            a0 = fmaf(x0.x, w0.x, a0); a0 = fmaf(x0.y, w0.y, a0); a0 = fmaf(x0.z, w0.z, a0); a0 = fmaf(x0.w, w0.w, a0);
            a1 = fmaf(x1.x, w1.x, a1); a1 = fmaf(x1.y, w1.y, a1); a1 = fmaf(x1.z, w1.z, a1); a1 = fmaf(x1.w, w1.w, a1);
            a2 = fmaf(x2.x, w2.x, a2); a2 = fmaf(x2.y, w2.y, a2); a2 = fmaf(x2.z, w2.z, a2); a2 = fmaf(x2.w, w2.w, a2);
            a3 = fmaf(x3.x, w3.x, a3); a3 = fmaf(x3.y, w3.y, a3); a3 = fmaf(x3.z, w3.z, a3); a3 = fmaf(x3.w, w3.w, a3);
        }
        #pragma unroll
        for (int kq = 0; kq < 8; kq += 4) {
            float4 w0, w1, w2, w3;
            if constexpr (TW) {
                w0 = wp[(OFF_W2F >> 2) + (kq    ) * 64 + t];
                w1 = wp[(OFF_W2F >> 2) + (kq + 1) * 64 + t];
                w2 = wp[(OFF_W2F >> 2) + (kq + 2) * 64 + t];
                w3 = wp[(OFF_W2F >> 2) + (kq + 3) * 64 + t];
            } else {
                w0 = make_float4(f2w[(64+4*kq+0)*64+t],  f2w[(64+4*kq+1)*64+t],  f2w[(64+4*kq+2)*64+t],  f2w[(64+4*kq+3)*64+t]);
                w1 = make_float4(f2w[(64+4*kq+4)*64+t],  f2w[(64+4*kq+5)*64+t],  f2w[(64+4*kq+6)*64+t],  f2w[(64+4*kq+7)*64+t]);
                w2 = make_float4(f2w[(64+4*kq+8)*64+t],  f2w[(64+4*kq+9)*64+t],  f2w[(64+4*kq+10)*64+t], f2w[(64+4*kq+11)*64+t]);
                w3 = make_float4(f2w[(64+4*kq+12)*64+t], f2w[(64+4*kq+13)*64+t], f2w[(64+4*kq+14)*64+t], f2w[(64+4*kq+15)*64+t]);
            }
            float f0 = sb[S_OBS + 210 + 4*kq + 0],  f1v = sb[S_OBS + 210 + 4*kq + 1];
            float f2v = sb[S_OBS + 210 + 4*kq + 2], f3v = sb[S_OBS + 210 + 4*kq + 3];
            float f4 = sb[S_OBS + 210 + 4*kq + 4],  f5 = sb[S_OBS + 210 + 4*kq + 5];
            float f6 = sb[S_OBS + 210 + 4*kq + 6],  f7 = sb[S_OBS + 210 + 4*kq + 7];
            float f8 = sb[S_OBS + 210 + 4*kq + 8],  f9 = sb[S_OBS + 210 + 4*kq + 9];
            float fa = sb[S_OBS + 210 + 4*kq + 10], fb = sb[S_OBS + 210 + 4*kq + 11];
            float fc = sb[S_OBS + 210 + 4*kq + 12], fd = sb[S_OBS + 210 + 4*kq + 13];
            float fe = sb[S_OBS + 210 + 4*kq + 14], ff = sb[S_OBS + 210 + 4*kq + 15];
            a0 = fmaf(f0, w0.x, a0); a0 = fmaf(f1v, w0.y, a0); a0 = fmaf(f2v, w0.z, a0); a0 = fmaf(f3v, w0.w, a0);
            a1 = fmaf(f4, w1.x, a1); a1 = fmaf(f5, w1.y, a1);  a1 = fmaf(f6, w1.z, a1);  a1 = fmaf(f7, w1.w, a1);
            a2 = fmaf(f8, w2.x, a2); a2 = fmaf(f9, w2.y, a2);  a2 = fmaf(fa, w2.z, a2);  a2 = fmaf(fb, w2.w, a2);
            a3 = fmaf(fc, w3.x, a3); a3 = fmaf(fd, w3.y, a3);  a3 = fmaf(fe, w3.z, a3);  a3 = fmaf(ff, w3.w, a3);
        }
        base_t = (a0 + a1) + (a2 + a3);
    }
    __syncthreads();   // W2act staged; s_meta visible

    // ---- agents ----
    const float* W2id = f2w + 96 * 64;
    float hacc = 0.f, cnt = 0.f;
    for (int a = 0; a < 20; ++a) {
        int m = s_meta[a];
        int mode = (m >> 5) & 3;
        if (mode == 0) continue;                 // wave-uniform
        int id = (m >> 8) - 2;
        int js = (m & 31) - 1;
        float idr = (id >= 0) ? W2id[id * 64 + t] : 0.f;
        float u = base_t + idr;
        if (mode == 1) {                         // expand: sum_j relu(u + W2act[j])
            float h0 = 0.f, h1 = 0.f, h2 = 0.f;
            #pragma unroll
            for (int j = 0; j < ACTN; j += 3) {
                h0 += fmaxf(u + sb[S_W2A + (j    ) * 64 + t], 0.f);
                h1 += fmaxf(u + sb[S_W2A + (j + 1) * 64 + t], 0.f);
                h2 += fmaxf(u + sb[S_W2A + (j + 2) * 64 + t], 0.f);
            }
            hacc += (h0 + h1) + h2;
            cnt  += 21.f;
        } else {                                 // single action (or none)
            float ar = (js >= 0) ? sb[S_W2A + js * 64 + t] : 0.f;
            hacc += fmaxf(u + ar, 0.f);
            cnt  += 1.f;
        }
    }
    sb[S_H + t] = hacc;
    __syncthreads();

    // ---- final: q = hacc @ fc3_w + cnt*fc3_b ----
    if (t < ACTN) {
        float q0 = cnt * f3b[t], q1 = 0.f, q2 = 0.f, q3 = 0.f;
        const float4* hp = (const float4*)&sb[S_H];
        #pragma unroll
        for (int hq = 0; hq < 16; hq += 4) {
            float4 h0 = hp[hq], h1 = hp[hq + 1], h2 = hp[hq + 2], h3 = hp[hq + 3];
            float4 w0, w1, w2, w3;
            if constexpr (TW) {
                w0 = wp[(OFF_F3 >> 2) + (hq    ) * 21 + t];
                w1 = wp[(OFF_F3 >> 2) + (hq + 1) * 21 + t];
                w2 = wp[(OFF_F3 >> 2) + (hq + 2) * 21 + t];
                w3 = wp[(OFF_F3 >> 2) + (hq + 3) * 21 + t];
            } else {
                w0 = make_float4(f3w[(4*hq+0)*21+t],  f3w[(4*hq+1)*21+t],  f3w[(4*hq+2)*21+t],  f3w[(4*hq+3)*21+t]);
                w1 = make_float4(f3w[(4*hq+4)*21+t],  f3w[(4*hq+5)*21+t],  f3w[(4*hq+6)*21+t],  f3w[(4*hq+7)*21+t]);
                w2 = make_float4(f3w[(4*hq+8)*21+t],  f3w[(4*hq+9)*21+t],  f3w[(4*hq+10)*21+t], f3w[(4*hq+11)*21+t]);
                w3 = make_float4(f3w[(4*hq+12)*21+t], f3w[(4*hq+13)*21+t], f3w[(4*hq+14)*21+t], f3w[(4*hq+15)*21+t]);
            }
            q0 = fmaf(h0.x, w0.x, q0); q0 = fmaf(h0.y, w0.y, q0); q0 = fmaf(h0.z, w0.z, q0); q0 = fmaf(h0.w, w0.w, q0);
            q1 = fmaf(h1.x, w1.x, q1); q1 = fmaf(h1.y, w1.y, q1); q1 = fmaf(h1.z, w1.z, q1); q1 = fmaf(h1.w, w1.w, q1);
            q2 = fmaf(h2.x, w2.x, q2); q2 = fmaf(h2.y, w2.y, q2); q2 = fmaf(h2.z, w2.z, q2); q2 = fmaf(h2.w, w2.w, q2);
            q3 = fmaf(h3.x, w3.x, q3); q3 = fmaf(h3.y, w3.y, q3); q3 = fmaf(h3.z, w3.z, q3); q3 = fmaf(h3.w, w3.w, q3);
        }
        out[b * 21 + t] = (q0 + q1) + (q2 + q3);
    }
}

extern "C" void kernel_launch(void* const* d_in, const int* in_sizes, int n_in,
                              void* d_out, int out_size, void* d_ws, size_t ws_size,
                              hipStream_t stream) {
    const float* obs = (const float*)d_in[0];
    const float* c1w = (const float*)d_in[1];
    const float* c1b = (const float*)d_in[2];
    const float* c2w = (const float*)d_in[3];
    const float* c2b = (const float*)d_in[4];
    const float* f1w = (const float*)d_in[5];
    const float* f1b = (const float*)d_in[6];
    const float* f2w = (const float*)d_in[7];
    const float* f2b = (const float*)d_in[8];
    const float* f3w = (const float*)d_in[9];
    const float* f3b = (const float*)d_in[10];
    float* ws = (float*)d_ws;
    float* o  = (float*)d_out;

    const bool tw = ws_size >= (size_t)WS_FLOATS * sizeof(float);
    if (tw) {
        repack_k<<<(SEG_END + 255) / 256, 256, 0, stream>>>(c1w, c2w, f1w, f2w, f3w, ws);
        fused_k<true><<<4096, 64, 0, stream>>>(obs, c1w, c1b, c2w, c2b, f1w, f1b,
                                               f2w, f2b, f3w, f3b, ws, o);
    } else {
        fused_k<false><<<4096, 64, 0, stream>>>(obs, c1w, c1b, c2w, c2b, f1w, f1b,
                                                f2w, f2b, f3w, f3b, ws, o);
    }
}

// Round 4
// 44.029 us; speedup vs baseline: 2.1205x; 2.0104x over previous
//
#include <hip/hip_runtime.h>

constexpr int OBS   = 682;   // 210 view + 32 feat + 440 nb
constexpr int ACTN  = 21;
constexpr int C1W_N = 1440;  // 32*5*3*3
constexpr int C2W_N = 9216;  // 32*32*3*3

// Transpose conv weights: [oc][k] -> [k][oc]  (k = c*9 + kh*3 + kw)
__global__ void transpose_w_k(const float* __restrict__ c1w,
                              const float* __restrict__ c2w,
                              float* __restrict__ ws) {
    int idx = blockIdx.x * 256 + threadIdx.x;
    if (idx < C1W_N) {
        int oc = idx / 45, x = idx - oc * 45;
        ws[x * 32 + oc] = c1w[idx];
    }
    int i2 = idx - C1W_N;
    if (i2 >= 0 && i2 < C2W_N) {
        int oc = i2 / 288, x = i2 - oc * 288;
        ws[C1W_N + x * 32 + oc] = c2w[i2];
    }
}

__device__ __forceinline__ float comp4(float4 v, int i) {
    return (i == 0) ? v.x : (i == 1) ? v.y : (i == 2) ? v.z : v.w;
}

template <bool TW>
__global__ __launch_bounds__(64, 4) void fused_k(
    const float* __restrict__ obs,
    const float* __restrict__ c1w, const float* __restrict__ c1b,
    const float* __restrict__ c2w, const float* __restrict__ c2b,
    const float* __restrict__ f1w, const float* __restrict__ f1b,
    const float* __restrict__ f2w, const float* __restrict__ f2b,
    const float* __restrict__ f3w, const float* __restrict__ f3b,
    const float* __restrict__ wt,
    float* __restrict__ out)
{
    const int b = blockIdx.x;
    const int t = threadIdx.x;

    __shared__ __align__(16) float s_obs[OBS];  // view | feat | nb
    __shared__ __align__(16) float s_c1[640];   // [ic][h=5][w=4]
    __shared__ __align__(16) float s_part[384]; // [half][oc][6]
    __shared__ __align__(16) float s_c2[192];   // [oc][pos=6]
    __shared__ __align__(16) float s_x[64];
    __shared__ __align__(16) float s_h[64];
    __shared__ int s_meta[20];

    const float* orow = obs + (long)b * OBS;
    for (int i = t; i < OBS; i += 64) s_obs[i] = orow[i];
    __syncthreads();

    // ---- agent meta scan (acts one-hot or zero); consumed after later syncs ----
    if (t < 20) {
        const float* nb = &s_obs[242 + t * 22];
        int id = (int)nb[0];
        int js = -1;
        #pragma unroll
        for (int j = 0; j < ACTN; ++j) {
            float av = nb[1 + j];
            js = (av != 0.f && js < 0) ? j : js;
        }
        int mode = (id < -1) ? 0 : ((id >= 0 && js < 0) ? 1 : 2);
        s_meta[t] = ((id + 2) << 8) | (mode << 5) | (js + 1);
    }

    // ---------------- conv1: (5,7,6) -> (32,5,4), relu  (exactly R1) ----------------
    {
        const int oc = t & 31, ph = t >> 5;   // ow in {ph, ph+2}
        float acc[10];
        #pragma unroll
        for (int i = 0; i < 10; ++i) acc[i] = 0.f;
        #pragma unroll
        for (int c = 0; c < 5; ++c) {
            float w[9];
            #pragma unroll
            for (int k = 0; k < 9; ++k)
                w[k] = TW ? wt[(c * 9 + k) * 32 + oc] : c1w[oc * 45 + c * 9 + k];
            #pragma unroll
            for (int r = 0; r < 7; ++r) {
                float rv[5];
                #pragma unroll
                for (int j = 0; j < 5; ++j) rv[j] = s_obs[c * 42 + r * 6 + ph + j];
                #pragma unroll
                for (int kh = 0; kh < 3; ++kh) {
                    int oh = r - kh;
                    if (oh < 0 || oh > 4) continue;
                    #pragma unroll
                    for (int kw = 0; kw < 3; ++kw) {
                        acc[oh * 2 + 0] = fmaf(rv[kw],     w[kh * 3 + kw], acc[oh * 2 + 0]);
                        acc[oh * 2 + 1] = fmaf(rv[kw + 2], w[kh * 3 + kw], acc[oh * 2 + 1]);
                    }
                }
            }
        }
        float bias = c1b[oc];
        #pragma unroll
        for (int oh = 0; oh < 5; ++oh)
            #pragma unroll
            for (int owi = 0; owi < 2; ++owi)
                s_c1[oc * 20 + oh * 4 + ph + 2 * owi] = fmaxf(acc[oh * 2 + owi] + bias, 0.f);
    }
    __syncthreads();

    // ---- conv2: (32,5,4) -> (32,3,2); all 64 lanes via ic-split, aligned reads ----
    {
        const int oc = t & 31, half = t >> 5;   // half: ic 0..15 / 16..31
        float a0 = 0.f, a1 = 0.f, a2 = 0.f, a3 = 0.f, a4 = 0.f, a5 = 0.f; // (oh,ow)
        #pragma unroll 4
        for (int icc = 0; icc < 16; ++icc) {
            const int ic = half * 16 + icc;
            const float4* rp = (const float4*)&s_c1[ic * 20];
            float4 r0 = rp[0], r1 = rp[1], r2 = rp[2], r3 = rp[3], r4 = rp[4];
            float w[9];
            #pragma unroll
            for (int k = 0; k < 9; ++k)
                w[k] = TW ? wt[C1W_N + (ic * 9 + k) * 32 + oc] : c2w[oc * 288 + ic * 9 + k];
            #pragma unroll
            for (int kh = 0; kh < 3; ++kh) {
                float4 ra = (kh == 0) ? r0 : (kh == 1) ? r1 : r2;   // row kh   (oh=0)
                float4 rb = (kh == 0) ? r1 : (kh == 1) ? r2 : r3;   // row kh+1 (oh=1)
                float4 rc = (kh == 0) ? r2 : (kh == 1) ? r3 : r4;   // row kh+2 (oh=2)
                #pragma unroll
                for (int kw = 0; kw < 3; ++kw) {
                    float ww = w[kh * 3 + kw];
                    a0 = fmaf(comp4(ra, kw),     ww, a0);
                    a1 = fmaf(comp4(ra, kw + 1), ww, a1);
                    a2 = fmaf(comp4(rb, kw),     ww, a2);
                    a3 = fmaf(comp4(rb, kw + 1), ww, a3);
                    a4 = fmaf(comp4(rc, kw),     ww, a4);
                    a5 = fmaf(comp4(rc, kw + 1), ww, a5);
                }
            }
        }
        float* pp = &s_part[(half * 32 + oc) * 6];
        pp[0] = a0; pp[1] = a1; pp[2] = a2; pp[3] = a3; pp[4] = a4; pp[5] = a5;
    }
    __syncthreads();
    if (t < 32) {
        float bias = c2b[t];
        #pragma unroll
        for (int p = 0; p < 6; ++p)
            s_c2[t * 6 + p] = fmaxf(s_part[t * 6 + p] + s_part[(32 + t) * 6 + p] + bias, 0.f);
    }
    __syncthreads();

    // ---------------- fc1: 192 -> 64, relu (2 accumulators, R1 loads) ----------------
    {
        float a0 = f1b[t], a1 = 0.f;
        #pragma unroll 4
        for (int i4 = 0; i4 < 48; ++i4) {
            float4 v = ((const float4*)s_c2)[i4];
            a0 = fmaf(v.x, f1w[(i4 * 4 + 0) * 64 + t], a0);
            a1 = fmaf(v.y, f1w[(i4 * 4 + 1) * 64 + t], a1);
            a0 = fmaf(v.z, f1w[(i4 * 4 + 2) * 64 + t], a0);
            a1 = fmaf(v.w, f1w[(i4 * 4 + 3) * 64 + t], a1);
        }
        s_x[t] = fmaxf(a0 + a1, 0.f);
    }
    __syncthreads();

    // ---------------- base = x@W2x + feat@W2f + b2 (2 accumulators) ----------------
    float base_t;
    {
        const float* W2x = f2w;             // rows [0,64)
        const float* W2f = f2w + 64 * 64;   // rows [64,96)
        float a0 = f2b[t], a1 = 0.f;
        #pragma unroll 4
        for (int i4 = 0; i4 < 16; ++i4) {
            float4 v = ((const float4*)s_x)[i4];
            a0 = fmaf(v.x, W2x[(i4 * 4 + 0) * 64 + t], a0);
            a1 = fmaf(v.y, W2x[(i4 * 4 + 1) * 64 + t], a1);
            a0 = fmaf(v.z, W2x[(i4 * 4 + 2) * 64 + t], a0);
            a1 = fmaf(v.w, W2x[(i4 * 4 + 3) * 64 + t], a1);
        }
        const float2* fp = (const float2*)&s_obs[210];  // 8B-aligned (210 even)
        #pragma unroll 4
        for (int i2 = 0; i2 < 16; ++i2) {
            float2 v = fp[i2];
            a0 = fmaf(v.x, W2f[(i2 * 2 + 0) * 64 + t], a0);
            a1 = fmaf(v.y, W2f[(i2 * 2 + 1) * 64 + t], a1);
        }
        base_t = a0 + a1;
    }

    // ---------------- agents (meta-driven; W2act from global like R1) ----------------
    const float* W2id  = f2w + 96 * 64;
    const float* W2act = f2w + 116 * 64;
    float hacc = 0.f, cnt = 0.f;
    for (int a = 0; a < 20; ++a) {
        int m = s_meta[a];
        int mode = (m >> 5) & 3;
        if (mode == 0) continue;               // wave-uniform skip
        int id = (m >> 8) - 2;
        int js = (m & 31) - 1;
        float u = base_t + ((id >= 0) ? W2id[id * 64 + t] : 0.f);
        if (mode == 1) {                        // expand: sum_j relu(u + W2act[j])
            float h0 = 0.f, h1 = 0.f, h2 = 0.f;
            #pragma unroll
            for (int j = 0; j < ACTN; j += 3) {
                h0 += fmaxf(u + W2act[(j    ) * 64 + t], 0.f);
                h1 += fmaxf(u + W2act[(j + 1) * 64 + t], 0.f);
                h2 += fmaxf(u + W2act[(j + 2) * 64 + t], 0.f);
            }
            hacc += (h0 + h1) + h2;
            cnt  += 21.f;
        } else {                                // single action (or none, id==-1)
            float ar = (js >= 0) ? W2act[js * 64 + t] : 0.f;
            hacc += fmaxf(u + ar, 0.f);
            cnt  += 1.f;
        }
    }
    s_h[t] = hacc;
    __syncthreads();

    // ---------------- final: q = hacc @ fc3_w + cnt*fc3_b (2 accumulators) ----------------
    if (t < ACTN) {
        float q0 = cnt * f3b[t], q1 = 0.f;
        #pragma unroll 4
        for (int h4 = 0; h4 < 16; ++h4) {
            float4 v = ((const float4*)s_h)[h4];
            q0 = fmaf(v.x, f3w[(h4 * 4 + 0) * 21 + t], q0);
            q1 = fmaf(v.y, f3w[(h4 * 4 + 1) * 21 + t], q1);
            q0 = fmaf(v.z, f3w[(h4 * 4 + 2) * 21 + t], q0);
            q1 = fmaf(v.w, f3w[(h4 * 4 + 3) * 21 + t], q1);
        }
        out[b * 21 + t] = q0 + q1;
    }
}

extern "C" void kernel_launch(void* const* d_in, const int* in_sizes, int n_in,
                              void* d_out, int out_size, void* d_ws, size_t ws_size,
                              hipStream_t stream) {
    const float* obs = (const float*)d_in[0];
    const float* c1w = (const float*)d_in[1];
    const float* c1b = (const float*)d_in[2];
    const float* c2w = (const float*)d_in[3];
    const float* c2b = (const float*)d_in[4];
    const float* f1w = (const float*)d_in[5];
    const float* f1b = (const float*)d_in[6];
    const float* f2w = (const float*)d_in[7];
    const float* f2b = (const float*)d_in[8];
    const float* f3w = (const float*)d_in[9];
    const float* f3b = (const float*)d_in[10];
    float* ws = (float*)d_ws;
    float* o  = (float*)d_out;

    const bool tw = ws_size >= (size_t)(C1W_N + C2W_N) * sizeof(float);
    if (tw) {
        transpose_w_k<<<(C1W_N + C2W_N + 255) / 256, 256, 0, stream>>>(c1w, c2w, ws);
        fused_k<true><<<4096, 64, 0, stream>>>(obs, c1w, c1b, c2w, c2b, f1w, f1b,
                                               f2w, f2b, f3w, f3b, ws, o);
    } else {
        fused_k<false><<<4096, 64, 0, stream>>>(obs, c1w, c1b, c2w, c2b, f1w, f1b,
                                                f2w, f2b, f3w, f3b, ws, o);
    }
}